// Round 6
// baseline (277.749 us; speedup 1.0000x reference)
//
#include <hip/hip_runtime.h>
#include <math.h>

#define B_   64
#define N_   197
#define C_   768
#define H_   12
#define D_   64
#define BN   12608      // B_*N_
#define BN_PAD 12672    // 99*128 (GEMM M padded)
#define QKV_PAD 12582912    // 64*12*256*64 elems per tensor (padded layout)
#define HSTR 16384          // per-(b,h) stride (256*64)
#define SCALE 0.125f    // D^-0.5
#define STRV 80         // Ps LDS row stride (ushorts)

typedef unsigned short ushort_t;
using bf16x8  = __attribute__((ext_vector_type(8))) __bf16;
using floatx4 = __attribute__((ext_vector_type(4))) float;

__device__ __forceinline__ ushort_t f2bf(float f) {
    union { float f; unsigned u; } v; v.f = f;
    unsigned r = v.u + 0x7FFF + ((v.u >> 16) & 1);   // RNE
    return (ushort_t)(r >> 16);
}

__device__ __forceinline__ void gload_lds16(const void* g, void* l) {
    __builtin_amdgcn_global_load_lds(
        (const __attribute__((address_space(1))) unsigned*)g,
        (__attribute__((address_space(3))) unsigned*)l, 16, 0, 0);
}

// ---------------------------------------------------------------------------
// Fused fp32->bf16 conversion for x, qkv_w, proj_w (one launch).
// ---------------------------------------------------------------------------
#define NX4 2420736
#define NW4 442368
#define NP4 147456
__global__ __launch_bounds__(256) void cvt_all(
    const float* __restrict__ x, const float* __restrict__ qw,
    const float* __restrict__ pw,
    ushort_t* __restrict__ xb, ushort_t* __restrict__ wb,
    ushort_t* __restrict__ pwb)
{
    int i = blockIdx.x * 256 + threadIdx.x;
    const float* s; ushort_t* d; int off;
    if (i < NX4)                { s = x;  d = xb;  off = i; }
    else if (i < NX4 + NW4)     { s = qw; d = wb;  off = i - NX4; }
    else if (i < NX4 + NW4+NP4) { s = pw; d = pwb; off = i - NX4 - NW4; }
    else return;
    float4 v = ((const float4*)s)[off];
    ushort4 o;
    o.x = f2bf(v.x); o.y = f2bf(v.y); o.z = f2bf(v.z); o.w = f2bf(v.w);
    ((ushort4*)d)[off] = o;
}

// ---------------------------------------------------------------------------
// Relative-position-bias precompute: rpb[12][256][256] bf16.
// Rows/cols >=197 get bf16 -inf (0xFF80): serves as the column mask, so the
// attention kernel needs NO masking branch and NO index math.
// ---------------------------------------------------------------------------
__global__ __launch_bounds__(256) void rpb_precompute(
    const float* __restrict__ rel_table,   // [732, 12]
    ushort_t* __restrict__ rpb)
{
    const int i = blockIdx.x * 256 + threadIdx.x;   // 65536 = 256x256
    const int n = i >> 8, m = i & 255;
    if (n >= 197 || m >= 197) {
#pragma unroll
        for (int h = 0; h < 12; ++h) rpb[h * 65536 + i] = 0xFF80;  // -inf
        return;
    }
    int idx;
    if (n == 0 && m == 0)      idx = 731;
    else if (n == 0)           idx = 729;
    else if (m == 0)           idx = 730;
    else {
        const int p = n - 1, q = m - 1;
        idx = (p / 14 - q / 14 + 13) * 27 + (p % 14 - q % 14 + 13);
    }
#pragma unroll
    for (int h = 0; h < 12; ++h)
        rpb[h * 65536 + i] = f2bf(rel_table[idx * 12 + h]);
}

// ---------------------------------------------------------------------------
// Kernel 1: QKV projection GEMM, bf16 MFMA, BK=64.
// Epilogue writes padded layouts: Q,K as [B,H,256,64] (Q scaled), V
// TRANSPOSED as [B,H,64,256] so attention can DMA-stage V^T directly.
// Pad rows/cols are never written (poison there is finite bf16; the rpb
// -inf mask kills those columns in softmax).
// ---------------------------------------------------------------------------
__global__ __launch_bounds__(256, 4) void qkv_gemm_mfma(
    const ushort_t* __restrict__ xb,   // [BN_PAD, 768] bf16
    const ushort_t* __restrict__ wb,   // [2304, 768] bf16
    const float* __restrict__ qb,
    const float* __restrict__ kb,
    const float* __restrict__ vb,
    ushort_t* __restrict__ qkvb)       // Q,K: [B,H,256,64]; V^T: [B,H,64,256]
{
    __shared__ ushort_t lA[128 * 64];
    __shared__ ushort_t lB[128 * 64];
    const int t = threadIdx.x;
    const int w = t >> 6, lane = t & 63;
    const int quad = lane >> 4, li = lane & 15;
    const int wm = w >> 1, wn = w & 1;
    const int o0 = blockIdx.x * 128, m0 = blockIdx.y * 128;

    floatx4 acc[4][4];
#pragma unroll
    for (int i = 0; i < 4; ++i)
#pragma unroll
        for (int j = 0; j < 4; ++j) acc[i][j] = (floatx4)0.f;

    const int rloc = lane >> 3;            // row within 8-row DMA chunk
    const int gdma = (lane & 7) ^ rloc;    // swizzled global granule
    const int rx   = li & 7;               // frag-read un-swizzle key

    for (int kt = 0; kt < 12; ++kt) {
        const int k0 = kt * 64;
#pragma unroll
        for (int s = 0; s < 4; ++s) {
            const int rb = w * 32 + s * 8;
            gload_lds16(xb + ((size_t)(m0 + rb + rloc)) * 768 + k0 + gdma * 8,
                        &lA[rb * 64]);
            gload_lds16(wb + ((size_t)(o0 + rb + rloc)) * 768 + k0 + gdma * 8,
                        &lB[rb * 64]);
        }
        __syncthreads();
#pragma unroll
        for (int kk = 0; kk < 2; ++kk) {
            bf16x8 af[4], bfr[4];
#pragma unroll
            for (int mi = 0; mi < 4; ++mi)
                af[mi] = *(const bf16x8*)
                    &lA[(wm * 64 + mi * 16 + li) * 64 + ((kk * 4 + quad) ^ rx) * 8];
#pragma unroll
            for (int ni = 0; ni < 4; ++ni)
                bfr[ni] = *(const bf16x8*)
                    &lB[(wn * 64 + ni * 16 + li) * 64 + ((kk * 4 + quad) ^ rx) * 8];
#pragma unroll
            for (int mi = 0; mi < 4; ++mi)
#pragma unroll
                for (int ni = 0; ni < 4; ++ni)
                    acc[mi][ni] = __builtin_amdgcn_mfma_f32_16x16x32_bf16(
                        af[mi], bfr[ni], acc[mi][ni], 0, 0, 0);
        }
        __syncthreads();
    }

    const int which = o0 / 768;
    const float* bias = (which == 0) ? qb : ((which == 1) ? kb : vb);
    ushort_t* dst = qkvb + (size_t)which * QKV_PAD;
    const float sc = (which == 0) ? SCALE : 1.0f;

#pragma unroll
    for (int mi = 0; mi < 4; ++mi) {
#pragma unroll
        for (int r = 0; r < 4; ++r) {
            const int m = m0 + wm * 64 + mi * 16 + quad * 4 + r;
            if (m < BN) {
                const int b = m / 197, n = m % 197;
#pragma unroll
                for (int ni = 0; ni < 4; ++ni) {
                    const int o  = o0 + wn * 64 + ni * 16 + li;
                    const int ol = o - which * 768;
                    const int h = ol >> 6, d = ol & 63;
                    const float v = (acc[mi][ni][r] + bias[ol]) * sc;
                    if (which < 2)
                        dst[((size_t)(b * 12 + h) * 256 + n) * 64 + d] = f2bf(v);
                    else
                        dst[((size_t)(b * 12 + h) * 64 + d) * 256 + n] = f2bf(v);
                }
            }
        }
    }
}

// ---------------------------------------------------------------------------
// Kernel 2: fused MFMA attention.  R6: bias from precomputed rpb (16 L2-hot
// scalar loads/chunk/lane, no index math, no mask branch); V^T staged by DMA
// into swizzled Vt[64][64] (transpose deleted).  LDS 34.8 KB -> 4 blocks/CU.
// ---------------------------------------------------------------------------
__global__ __launch_bounds__(256, 4) void attn_mfma(
    const ushort_t* __restrict__ qkvb,
    const ushort_t* __restrict__ rpb,     // [12][256][256] bf16, -inf padded
    ushort_t* __restrict__ aout)          // [BN, 768] bf16
{
    __shared__ ushort_t Qs[64 * 64];
    __shared__ ushort_t Ks[64 * 64];
    __shared__ ushort_t Vt[64 * 64];
    __shared__ ushort_t Ps[64 * STRV];

    const int rt = blockIdx.x, bh = blockIdx.y;
    const int h = bh % 12, bb = bh / 12;
    const int t = threadIdx.x;
    const int w = t >> 6, lane = t & 63, quad = lane >> 4, li = lane & 15;
    const ushort_t* Qg = qkvb + (size_t)bh * HSTR;
    const ushort_t* Kg = qkvb + (size_t)QKV_PAD + (size_t)bh * HSTR;
    const ushort_t* Vg = qkvb + (size_t)2 * QKV_PAD + (size_t)bh * HSTR;
    const int r0 = rt * 64;

    const int rloc = lane >> 3, gdma = (lane & 7) ^ rloc;

    // stage Q tile rows r0..r0+63 (swizzled DMA)
#pragma unroll
    for (int s = 0; s < 2; ++s) {
        const int rb = w * 16 + s * 8;
        gload_lds16(Qg + (size_t)(r0 + rb + rloc) * 64 + gdma * 8, &Qs[rb * 64]);
    }

    // per-row bias base pointers (rows n = r0 + w*16 + quad*4 + r)
    int nrow[4];
    const ushort_t* brow[4];
#pragma unroll
    for (int r = 0; r < 4; ++r) {
        nrow[r] = r0 + w * 16 + quad * 4 + r;
        brow[r] = rpb + (size_t)h * 65536 + nrow[r] * 256;
    }

    float m_run[4], l_run[4];
    floatx4 accO[4];
#pragma unroll
    for (int r = 0; r < 4; ++r) { m_run[r] = -INFINITY; l_run[r] = 0.f; }
#pragma unroll
    for (int dt = 0; dt < 4; ++dt) accO[dt] = (floatx4)0.f;

    __syncthreads();

    bf16x8 aq0, aq1;
    {
        const int rq = w * 16 + li, rxq = rq & 7;
        aq0 = *(const bf16x8*)&Qs[rq * 64 + (quad ^ rxq) * 8];
        aq1 = *(const bf16x8*)&Qs[rq * 64 + ((4 + quad) ^ rxq) * 8];
    }

    for (int cc = 0; cc < 4; ++cc) {
        // ---- stage K chunk + V^T chunk (swizzled DMA) ----
#pragma unroll
        for (int s = 0; s < 2; ++s) {
            const int rb = w * 16 + s * 8;
            gload_lds16(Kg + (size_t)(cc * 64 + rb + rloc) * 64 + gdma * 8,
                        &Ks[rb * 64]);
            gload_lds16(Vg + (size_t)(rb + rloc) * 256 + cc * 64 + gdma * 8,
                        &Vt[rb * 64]);
        }
        // ---- prefetch bias (bf16 scalar loads, L2-hot) ----
        unsigned bu[4][4];
#pragma unroll
        for (int tl = 0; tl < 4; ++tl) {
            const int cg = cc * 64 + tl * 16 + li;
#pragma unroll
            for (int r = 0; r < 4; ++r)
                bu[tl][r] = brow[r][cg];
        }
        __syncthreads();

        // ---- S = Q K^T ----
        floatx4 sacc[4];
#pragma unroll
        for (int tl = 0; tl < 4; ++tl) {
            const int rk = tl * 16 + li, rxk = rk & 7;
            bf16x8 bk0 = *(const bf16x8*)&Ks[rk * 64 + (quad ^ rxk) * 8];
            bf16x8 bk1 = *(const bf16x8*)&Ks[rk * 64 + ((4 + quad) ^ rxk) * 8];
            floatx4 sa = (floatx4)0.f;
            sa = __builtin_amdgcn_mfma_f32_16x16x32_bf16(aq0, bk0, sa, 0, 0, 0);
            sa = __builtin_amdgcn_mfma_f32_16x16x32_bf16(aq1, bk1, sa, 0, 0, 0);
            sacc[tl] = sa;
        }

        // ---- add bias (pad cols = -inf -> masked) ----
#pragma unroll
        for (int tl = 0; tl < 4; ++tl)
#pragma unroll
            for (int r = 0; r < 4; ++r)
                sacc[tl][r] += __uint_as_float(bu[tl][r] << 16);

        // ---- online softmax (fp32) + P -> LDS (bf16) ----
#pragma unroll
        for (int r = 0; r < 4; ++r) {
            float mx = fmaxf(fmaxf(sacc[0][r], sacc[1][r]),
                             fmaxf(sacc[2][r], sacc[3][r]));
            mx = fmaxf(mx, __shfl_xor(mx, 1));
            mx = fmaxf(mx, __shfl_xor(mx, 2));
            mx = fmaxf(mx, __shfl_xor(mx, 4));
            mx = fmaxf(mx, __shfl_xor(mx, 8));
            const float mnew = fmaxf(m_run[r], mx);
            const float alpha = __expf(m_run[r] - mnew);
            m_run[r] = mnew;
            const float p0 = __expf(sacc[0][r] - mnew);
            const float p1 = __expf(sacc[1][r] - mnew);
            const float p2 = __expf(sacc[2][r] - mnew);
            const float p3 = __expf(sacc[3][r] - mnew);
            float rs = p0 + p1 + p2 + p3;
            rs += __shfl_xor(rs, 1);
            rs += __shfl_xor(rs, 2);
            rs += __shfl_xor(rs, 4);
            rs += __shfl_xor(rs, 8);
            l_run[r] = l_run[r] * alpha + rs;
#pragma unroll
            for (int dt = 0; dt < 4; ++dt) accO[dt][r] *= alpha;
            const int prow = w * 16 + quad * 4 + r;
            Ps[prow * STRV +  0 + li] = f2bf(p0);
            Ps[prow * STRV + 16 + li] = f2bf(p1);
            Ps[prow * STRV + 32 + li] = f2bf(p2);
            Ps[prow * STRV + 48 + li] = f2bf(p3);
        }

        // ---- O += P V (per-wave-private P section; Vt swizzled) ----
        {
            const int rp = w * 16 + li;
            bf16x8 pa0 = *(const bf16x8*)&Ps[rp * STRV + 0  + quad * 8];
            bf16x8 pa1 = *(const bf16x8*)&Ps[rp * STRV + 32 + quad * 8];
#pragma unroll
            for (int dt = 0; dt < 4; ++dt) {
                const int rv = dt * 16 + li, rxv = rv & 7;
                bf16x8 bv0 = *(const bf16x8*)&Vt[rv * 64 + (quad ^ rxv) * 8];
                bf16x8 bv1 = *(const bf16x8*)&Vt[rv * 64 + ((4 + quad) ^ rxv) * 8];
                accO[dt] = __builtin_amdgcn_mfma_f32_16x16x32_bf16(
                    pa0, bv0, accO[dt], 0, 0, 0);
                accO[dt] = __builtin_amdgcn_mfma_f32_16x16x32_bf16(
                    pa1, bv1, accO[dt], 0, 0, 0);
            }
        }
        __syncthreads();
    }

    // ---- finalize: /l, store bf16 to (B,N,C) ----
#pragma unroll
    for (int r = 0; r < 4; ++r) {
        const int n = nrow[r];
        if (n < 197) {
            const float inv = 1.0f / l_run[r];
            ushort_t* op = aout + ((size_t)(bb * 197 + n)) * 768 + h * 64;
#pragma unroll
            for (int dt = 0; dt < 4; ++dt)
                op[dt * 16 + li] = f2bf(accO[dt][r] * inv);
        }
    }
}

// ---------------------------------------------------------------------------
// Kernel 3: output projection GEMM, bf16 MFMA, BK=64 (unchanged from R5).
// ---------------------------------------------------------------------------
__global__ __launch_bounds__(256, 4) void proj_gemm_mfma(
    const ushort_t* __restrict__ ab,   // [BN_PAD, 768] bf16
    const ushort_t* __restrict__ wb,   // [768, 768] bf16
    const float* __restrict__ bias,    // [768]
    float* __restrict__ out)           // [BN, 768] fp32
{
    __shared__ ushort_t lA[128 * 64];
    __shared__ ushort_t lB[128 * 64];
    const int t = threadIdx.x;
    const int w = t >> 6, lane = t & 63;
    const int quad = lane >> 4, li = lane & 15;
    const int wm = w >> 1, wn = w & 1;
    const int o0 = blockIdx.x * 128, m0 = blockIdx.y * 128;

    floatx4 acc[4][4];
#pragma unroll
    for (int i = 0; i < 4; ++i)
#pragma unroll
        for (int j = 0; j < 4; ++j) acc[i][j] = (floatx4)0.f;

    const int rloc = lane >> 3;
    const int gdma = (lane & 7) ^ rloc;
    const int rx   = li & 7;

    for (int kt = 0; kt < 12; ++kt) {
        const int k0 = kt * 64;
#pragma unroll
        for (int s = 0; s < 4; ++s) {
            const int rb = w * 32 + s * 8;
            gload_lds16(ab + ((size_t)(m0 + rb + rloc)) * 768 + k0 + gdma * 8,
                        &lA[rb * 64]);
            gload_lds16(wb + ((size_t)(o0 + rb + rloc)) * 768 + k0 + gdma * 8,
                        &lB[rb * 64]);
        }
        __syncthreads();
#pragma unroll
        for (int kk = 0; kk < 2; ++kk) {
            bf16x8 af[4], bfr[4];
#pragma unroll
            for (int mi = 0; mi < 4; ++mi)
                af[mi] = *(const bf16x8*)
                    &lA[(wm * 64 + mi * 16 + li) * 64 + ((kk * 4 + quad) ^ rx) * 8];
#pragma unroll
            for (int ni = 0; ni < 4; ++ni)
                bfr[ni] = *(const bf16x8*)
                    &lB[(wn * 64 + ni * 16 + li) * 64 + ((kk * 4 + quad) ^ rx) * 8];
#pragma unroll
            for (int mi = 0; mi < 4; ++mi)
#pragma unroll
                for (int ni = 0; ni < 4; ++ni)
                    acc[mi][ni] = __builtin_amdgcn_mfma_f32_16x16x32_bf16(
                        af[mi], bfr[ni], acc[mi][ni], 0, 0, 0);
        }
        __syncthreads();
    }

#pragma unroll
    for (int mi = 0; mi < 4; ++mi) {
#pragma unroll
        for (int r = 0; r < 4; ++r) {
            const int m = m0 + wm * 64 + mi * 16 + quad * 4 + r;
            if (m < BN) {
                float* op = out + (size_t)m * 768;
#pragma unroll
                for (int ni = 0; ni < 4; ++ni) {
                    const int o = o0 + wn * 64 + ni * 16 + li;
                    op[o] = acc[mi][ni][r] + bias[o];
                }
            }
        }
    }
}

// ---------------------------------------------------------------------------
// ws layout (bytes):
//   [0, 75497472)              qkvb bf16: Q,K [B,H,256,64] + V^T [B,H,64,256]
//   [75497472, 77070336)       rpb bf16 [12][256][256]
//   [77070336, 96534528)       xb bf16 [12672 x 768]; aliased by aout
//   [96534528, 100073472)      wb bf16 [2304 x 768]
//   [100073472, 101253120)     pwb bf16 [768 x 768]
// ---------------------------------------------------------------------------
extern "C" void kernel_launch(void* const* d_in, const int* in_sizes, int n_in,
                              void* d_out, int out_size, void* d_ws, size_t ws_size,
                              hipStream_t stream)
{
    const float* x         = (const float*)d_in[0];
    const float* qkv_w     = (const float*)d_in[1];
    const float* q_bias    = (const float*)d_in[2];
    const float* k_bias    = (const float*)d_in[3];
    const float* v_bias    = (const float*)d_in[4];
    const float* rel_table = (const float*)d_in[5];
    const float* proj_w    = (const float*)d_in[6];
    const float* proj_b    = (const float*)d_in[7];
    float* out = (float*)d_out;

    char* ws = (char*)d_ws;
    ushort_t* qkvb  = (ushort_t*)ws;
    ushort_t* rpb   = (ushort_t*)(ws + 75497472);
    ushort_t* xb    = (ushort_t*)(ws + 77070336);
    ushort_t* aoutb = xb;                      // alias (xb dead after qkv_gemm)
    ushort_t* wb    = (ushort_t*)(ws + 96534528);
    ushort_t* pwb   = (ushort_t*)(ws + 100073472);

    cvt_all<<<(NX4 + NW4 + NP4 + 255) / 256, 256, 0, stream>>>(
        x, qkv_w, proj_w, xb, wb, pwb);
    rpb_precompute<<<256, 256, 0, stream>>>(rel_table, rpb);

    dim3 g1(18, 99);
    qkv_gemm_mfma<<<g1, 256, 0, stream>>>(xb, wb, q_bias, k_bias, v_bias, qkvb);

    dim3 g2(4, 768);
    attn_mfma<<<g2, 256, 0, stream>>>(qkvb, rpb, aoutb);

    dim3 g3(6, 99);
    proj_gemm_mfma<<<g3, 256, 0, stream>>>(aoutb, pwb, proj_b, out);
}